// Round 6
// baseline (1872.835 us; speedup 1.0000x reference)
//
#include <hip/hip_runtime.h>

typedef unsigned int uint;
typedef unsigned short ushort;
typedef unsigned long long u64;
typedef __attribute__((ext_vector_type(2))) float f32x2;

#define N_PTS 4096
#define B_SZ 16
#define M_PTS 1024
#define K_SMP 32
#define NROWS (B_SZ*M_PTS*K_SMP)   /* 524288 */
#define INV_CNT (1.0f/524288.0f)   /* exact: 2^-19 */

// ---------- helpers ----------
__device__ __forceinline__ float sqdist3(float ax,float ay,float az,float bx,float by,float bz){
  // exact-match of numpy/XLA f32: separate sub/mul/add, no FMA contraction
  float dx=__fsub_rn(ax,bx), dy=__fsub_rn(ay,by), dz=__fsub_rn(az,bz);
  return __fadd_rn(__fadd_rn(__fmul_rn(dx,dx),__fmul_rn(dy,dy)),__fmul_rn(dz,dz));
}
__device__ __forceinline__ ushort f2bf(float x){
  uint u = __float_as_uint(x);
  u = (u + 0x7fffu + ((u>>16)&1u)) >> 16;   // RNE
  return (ushort)u;
}
__device__ __forceinline__ float bf2f(uint u){ return __uint_as_float(u<<16); }

// packed f32 pair ops (VOP3P, IEEE RN per element -> bit-exact vs scalar)
__device__ __forceinline__ f32x2 pk_add(f32x2 a, f32x2 b){
  f32x2 d; asm("v_pk_add_f32 %0, %1, %2" : "=v"(d) : "v"(a), "v"(b)); return d;
}
__device__ __forceinline__ f32x2 pk_mul(f32x2 a, f32x2 b){
  f32x2 d; asm("v_pk_mul_f32 %0, %1, %2" : "=v"(d) : "v"(a), "v"(b)); return d;
}

template<int CTRL>
__device__ __forceinline__ uint dppu(uint v){
  return (uint)__builtin_amdgcn_update_dpp((int)v, (int)v, CTRL, 0xf, 0xf, false);
}
// scan-style merge stage: incoming lane has STRICTLY LOWER point indices, so
// lowest-index-on-tie == take incoming iff in.val >= own.val  (1 cmp + 2 cndmask)
template<int CTRL>
__device__ __forceinline__ void dppscan(float& v, uint& i){
  float ov = __uint_as_float(dppu<CTRL>(__float_as_uint(v)));
  uint  oi = dppu<CTRL>(i);
  bool tk = (ov >= v);
  v = tk ? ov : v;
  i = tk ? oi : i;
}

// ---------- 1. FPS: 256 threads/batch, 16 CONTIGUOUS points per lane ----------
// Contiguous ownership makes every reduction operand-pair index-ordered, so the
// exact lowest-index tie-break costs 3 ops/merge. Single barrier per step.
__global__ __launch_bounds__(256, 1) void fps_kernel(const float* __restrict__ xyz,
                                                     float* __restrict__ out_newxyz){
  const int b = blockIdx.x;
  const int t = threadIdx.x;
  __shared__ float4 sxyz[N_PTS];            // 64 KB: winner-coord broadcast fetch ONLY
  __shared__ __align__(8) uint2 xch[2][4];  // per-wave winner, parity dbuf
  const float* src = xyz + (size_t)b*N_PTS*3;
  const int p0 = t*16;
  f32x2 px[8], py[8], pz[8], dist[8];
  {
    const float4* s4 = (const float4*)(src + 3*p0);
    float4 v[12];
#pragma unroll
    for (int q=0;q<12;q++) v[q] = s4[q];
    const float* f = (const float*)v;
#pragma unroll
    for (int i=0;i<8;i++){
      px[i] = f32x2{f[6*i+0], f[6*i+3]};
      py[i] = f32x2{f[6*i+1], f[6*i+4]};
      pz[i] = f32x2{f[6*i+2], f[6*i+5]};
      dist[i] = f32x2{1e10f, 1e10f};
    }
#pragma unroll
    for (int i=0;i<16;i++)
      sxyz[p0+i] = make_float4(f[3*i], f[3*i+1], f[3*i+2], 0.f);
  }
  __syncthreads();
  float cx, cy, cz;
  { float4 c0 = sxyz[0]; cx=c0.x; cy=c0.y; cz=c0.z; }
  const int w = t >> 6, lane = t & 63;
  float* outx = out_newxyz + (size_t)b*M_PTS*3;
  for (int s = 0; s < M_PTS; ++s){
    if (t == 0){ outx[s*3+0]=cx; outx[s*3+1]=cy; outx[s*3+2]=cz; }
    // A: packed dist update (sub as add of exact negation; IEEE RN per op)
    const f32x2 ncx = f32x2{-cx,-cx}, ncy = f32x2{-cy,-cy}, ncz = f32x2{-cz,-cz};
#pragma unroll
    for (int q=0;q<8;q++){
      f32x2 dx = pk_add(px[q], ncx);
      f32x2 dy = pk_add(py[q], ncy);
      f32x2 dz = pk_add(pz[q], ncz);
      f32x2 d  = pk_add(pk_add(pk_mul(dx,dx), pk_mul(dy,dy)), pk_mul(dz,dz));
      dist[q].x = fminf(dist[q].x, d.x);
      dist[q].y = fminf(dist[q].y, d.y);
    }
    // local 16->1 tree, left operand always lower index, take right iff strictly >
    float v8[8]; uint i8[8];
#pragma unroll
    for (int j=0;j<8;j++){
      bool tb = dist[j].y > dist[j].x;
      v8[j] = tb ? dist[j].y : dist[j].x;
      i8[j] = tb ? (uint)(2*j+1) : (uint)(2*j);
    }
#pragma unroll
    for (int j=0;j<4;j++){
      bool tb = v8[2*j+1] > v8[2*j];
      v8[j] = tb ? v8[2*j+1] : v8[2*j];
      i8[j] = tb ? i8[2*j+1] : i8[2*j];
    }
    {
      bool tb = v8[1] > v8[0];
      v8[0] = tb ? v8[1] : v8[0]; i8[0] = tb ? i8[1] : i8[0];
      tb = v8[3] > v8[2];
      v8[1] = tb ? v8[3] : v8[2]; i8[1] = tb ? i8[3] : i8[2];
      tb = v8[1] > v8[0];
      v8[0] = tb ? v8[1] : v8[0]; i8[0] = tb ? i8[1] : i8[0];
    }
    float mv = v8[0];
    uint  gi = (uint)p0 + i8[0];
    // B: 64-lane inclusive-scan max (3 ops/stage) -> lane 63 = wave winner
    dppscan<0x111>(mv, gi);   // row_shr:1
    dppscan<0x112>(mv, gi);   // row_shr:2
    dppscan<0x114>(mv, gi);   // row_shr:4
    dppscan<0x118>(mv, gi);   // row_shr:8
    dppscan<0x142>(mv, gi);   // row_bcast:15
    dppscan<0x143>(mv, gi);   // row_bcast:31
    // C: cross-wave merge over 4 wave winners (wave w owns lower indices than w+1)
    const int par = s & 1;
    if (lane == 63) xch[par][w] = make_uint2(__float_as_uint(mv), gi);
    __syncthreads();
    uint2 cw = xch[par][lane & 3];
    float cv = __uint_as_float(cw.x); uint ci = cw.y;
    dppscan<0x111>(cv, ci);
    dppscan<0x112>(cv, ci);       // lane 3 = global winner
    uint fi = (uint)__builtin_amdgcn_readlane((int)ci, 3);
    float4 cc = sxyz[fi];         // uniform broadcast read
    cx = cc.x; cy = cc.y; cz = cc.z;
  }
}

// ---------- 2. ball query (exact f32, first-32 in index order) ----------
__global__ __launch_bounds__(256) void ballq_kernel(const float* __restrict__ xyz,
                                                    const float* __restrict__ newxyz,
                                                    int* __restrict__ gidx){
  const int blk = blockIdx.x;
  const int b = blk >> 6;
  const int mbase = (blk & 63) * 16;
  __shared__ float sx[N_PTS], sy[N_PTS], sz[N_PTS];
  const float* src = xyz + (size_t)b*N_PTS*3;
  for (int i = threadIdx.x; i < N_PTS*3; i += 256){
    float v = src[i]; int p = i/3, j = i%3;
    (j==0?sx:(j==1?sy:sz))[p] = v;
  }
  __syncthreads();
  const int w = threadIdx.x >> 6, lane = threadIdx.x & 63;
  const float R2 = (float)(0.2*0.2);   // f32(f64 product) — matches reference cast
  for (int mm = w; mm < 16; mm += 4){
    const int m = mbase + mm;
    const float* c = newxyz + ((size_t)b*M_PTS + m)*3;
    float cx = c[0], cy = c[1], cz = c[2];
    int* gout = gidx + ((size_t)b*M_PTS + m)*K_SMP;
    int cnt = 0;
    for (int base = 0; base < N_PTS && cnt < K_SMP; base += 64){
      int p = base + lane;
      float d = sqdist3(sx[p],sy[p],sz[p],cx,cy,cz);
      bool in = (d <= R2);
      unsigned long long mask = __ballot(in);
      int prefix = __popcll(mask & ((1ull << lane) - 1ull));
      int slot = cnt + prefix;
      if (in && slot < K_SMP) gout[slot] = p;
      cnt += __popcll(mask);
    }
    if (cnt < K_SMP){
      int slot = cnt + lane;
      if (slot < K_SMP) gout[slot] = 0;
    }
  }
}

// ---------- 3. conv0: gather + concat + 67->64 matmul (+bias), write bf16 ----------
__global__ __launch_bounds__(256, 2) void conv0_kernel(const float* __restrict__ xyz,
                                                       const float* __restrict__ points,
                                                       const float* __restrict__ newxyz,
                                                       const int* __restrict__ gidx,
                                                       const float* __restrict__ W0,
                                                       const float* __restrict__ b0,
                                                       ushort* __restrict__ x1){
  const int r = blockIdx.x*256 + threadIdx.x;         // 524288 rows
  const int b = r >> 15, m = (r >> 5) & 1023;
  const int g = gidx[r];
  const float* pc = newxyz + ((size_t)(b<<10) + m)*3;
  const float* pp = xyz    + ((size_t)(b<<12) + g)*3;
  float f[67];
  f[0]=pp[0]-pc[0]; f[1]=pp[1]-pc[1]; f[2]=pp[2]-pc[2];
  const float4* prow = (const float4*)(points + (((size_t)(b<<12) + g) << 6));
#pragma unroll
  for (int q=0;q<16;q++){
    float4 v = prow[q];
    f[3+4*q]=v.x; f[4+4*q]=v.y; f[5+4*q]=v.z; f[6+4*q]=v.w;
  }
  float acc[64];
#pragma unroll
  for (int o=0;o<64;o++) acc[o]=b0[o];
#pragma unroll
  for (int o=0;o<64;o++){
    const float* wr = W0 + o*67;
    float a = acc[o];
#pragma unroll
    for (int c=0;c<67;c++) a = fmaf(f[c], wr[c], a);
    acc[o]=a;
  }
  uint4* orow = (uint4*)(x1 + ((size_t)r << 6));
#pragma unroll
  for (int q=0;q<8;q++){
    uint4 v;
    v.x = (uint)f2bf(acc[q*8+0]) | ((uint)f2bf(acc[q*8+1])<<16);
    v.y = (uint)f2bf(acc[q*8+2]) | ((uint)f2bf(acc[q*8+3])<<16);
    v.z = (uint)f2bf(acc[q*8+4]) | ((uint)f2bf(acc[q*8+5])<<16);
    v.w = (uint)f2bf(acc[q*8+6]) | ((uint)f2bf(acc[q*8+7])<<16);
    orow[q]=v;
  }
}

// ---------- stats: per-channel sum & sumsq, vectorized 8 ch/thread ----------
template<int C>
__global__ __launch_bounds__(256) void stats_kernel(const ushort* __restrict__ x,
                                                    float* __restrict__ S,
                                                    float* __restrict__ SS){
  constexpr int GRP = C/8;            // 8-channel groups per row: 8 (C=64) / 16 (C=128)
  constexpr int RL  = 256/GRP;        // row lanes per block: 32 / 16
  const int cg = threadIdx.x % GRP;
  const int rl = threadIdx.x / GRP;
  const int rows_per_block = NROWS / 1024;   // grid = 1024
  const int r0 = blockIdx.x * rows_per_block;
  float s[8], ss[8];
#pragma unroll
  for (int j=0;j<8;j++){ s[j]=0.f; ss[j]=0.f; }
  for (int r = r0 + rl; r < r0 + rows_per_block; r += RL){
    uint4 v = *(const uint4*)(x + (size_t)r*C + cg*8);
    uint d[4] = {v.x, v.y, v.z, v.w};
#pragma unroll
    for (int q=0;q<4;q++){
      float a0 = bf2f(d[q] & 0xffffu), a1 = bf2f(d[q] >> 16);
      s[2*q]   += a0; ss[2*q]   = fmaf(a0, a0, ss[2*q]);
      s[2*q+1] += a1; ss[2*q+1] = fmaf(a1, a1, ss[2*q+1]);
    }
  }
  __shared__ float ls[256][8], lss[256][8];   // 16 KB
#pragma unroll
  for (int j=0;j<8;j++){ ls[threadIdx.x][j]=s[j]; lss[threadIdx.x][j]=ss[j]; }
  __syncthreads();
  if (threadIdx.x < C){
    const int grp = threadIdx.x >> 3, j = threadIdx.x & 7;
    float a = 0.f, q2 = 0.f;
#pragma unroll
    for (int q = 0; q < RL; q++){ a += ls[q*GRP + grp][j]; q2 += lss[q*GRP + grp][j]; }
    atomicAdd(&S[threadIdx.x], a); atomicAdd(&SS[threadIdx.x], q2);
  }
}

// ---------- conv1: BN0+ReLU fused on read, 64->64 ----------
__global__ __launch_bounds__(256, 2) void conv1_kernel(const ushort* __restrict__ x1,
                                                       const float* __restrict__ S0,
                                                       const float* __restrict__ SS0,
                                                       const float* __restrict__ g0,
                                                       const float* __restrict__ be0,
                                                       const float* __restrict__ W1,
                                                       const float* __restrict__ b1,
                                                       ushort* __restrict__ x2){
  __shared__ float sc[64], sh[64];
  if (threadIdx.x < 64){
    int c = threadIdx.x;
    float mean = S0[c]*INV_CNT;
    float var  = fmaf(-mean, mean, SS0[c]*INV_CNT);
    float is   = rsqrtf(var + 1e-5f);
    float scv  = g0[c]*is;
    sc[c] = scv; sh[c] = fmaf(-mean, scv, be0[c]);
  }
  __syncthreads();
  const size_t r = (size_t)blockIdx.x*256 + threadIdx.x;
  const uint4* row = (const uint4*)(x1 + (r<<6));
  float f[64];
#pragma unroll
  for (int q=0;q<8;q++){
    uint4 v = row[q];
    f[q*8+0]=bf2f(v.x&0xffffu); f[q*8+1]=bf2f(v.x>>16);
    f[q*8+2]=bf2f(v.y&0xffffu); f[q*8+3]=bf2f(v.y>>16);
    f[q*8+4]=bf2f(v.z&0xffffu); f[q*8+5]=bf2f(v.z>>16);
    f[q*8+6]=bf2f(v.w&0xffffu); f[q*8+7]=bf2f(v.w>>16);
  }
#pragma unroll
  for (int c=0;c<64;c++) f[c] = fmaxf(fmaf(f[c], sc[c], sh[c]), 0.f);
  float acc[64];
#pragma unroll
  for (int o=0;o<64;o++) acc[o]=b1[o];
#pragma unroll
  for (int o=0;o<64;o++){
    const float* wr = W1 + o*64;
    float a = acc[o];
#pragma unroll
    for (int c=0;c<64;c++) a = fmaf(f[c], wr[c], a);
    acc[o]=a;
  }
  uint4* orow = (uint4*)(x2 + (r<<6));
#pragma unroll
  for (int q=0;q<8;q++){
    uint4 v;
    v.x = (uint)f2bf(acc[q*8+0]) | ((uint)f2bf(acc[q*8+1])<<16);
    v.y = (uint)f2bf(acc[q*8+2]) | ((uint)f2bf(acc[q*8+3])<<16);
    v.z = (uint)f2bf(acc[q*8+4]) | ((uint)f2bf(acc[q*8+5])<<16);
    v.w = (uint)f2bf(acc[q*8+6]) | ((uint)f2bf(acc[q*8+7])<<16);
    orow[q]=v;
  }
}

// ---------- conv2: BN1+ReLU fused on read, 64->128 ----------
__global__ __launch_bounds__(256, 2) void conv2_kernel(const ushort* __restrict__ x2,
                                                       const float* __restrict__ S1,
                                                       const float* __restrict__ SS1,
                                                       const float* __restrict__ g1,
                                                       const float* __restrict__ be1,
                                                       const float* __restrict__ W2,
                                                       const float* __restrict__ b2,
                                                       ushort* __restrict__ x3){
  __shared__ float sc[64], sh[64];
  if (threadIdx.x < 64){
    int c = threadIdx.x;
    float mean = S1[c]*INV_CNT;
    float var  = fmaf(-mean, mean, SS1[c]*INV_CNT);
    float is   = rsqrtf(var + 1e-5f);
    float scv  = g1[c]*is;
    sc[c] = scv; sh[c] = fmaf(-mean, scv, be1[c]);
  }
  __syncthreads();
  const int lane = threadIdx.x & 63;
  const int wv   = threadIdx.x >> 6;
  const size_t r = (size_t)blockIdx.x*128 + (size_t)(wv>>1)*64 + lane;
  const int h = wv & 1;                       // wave-uniform output half
  const uint4* row = (const uint4*)(x2 + (r<<6));
  float f[64];
#pragma unroll
  for (int q=0;q<8;q++){
    uint4 v = row[q];
    f[q*8+0]=bf2f(v.x&0xffffu); f[q*8+1]=bf2f(v.x>>16);
    f[q*8+2]=bf2f(v.y&0xffffu); f[q*8+3]=bf2f(v.y>>16);
    f[q*8+4]=bf2f(v.z&0xffffu); f[q*8+5]=bf2f(v.z>>16);
    f[q*8+6]=bf2f(v.w&0xffffu); f[q*8+7]=bf2f(v.w>>16);
  }
#pragma unroll
  for (int c=0;c<64;c++) f[c] = fmaxf(fmaf(f[c], sc[c], sh[c]), 0.f);
  float acc[64];
#pragma unroll
  for (int o=0;o<64;o++) acc[o]=b2[h*64+o];
#pragma unroll
  for (int o=0;o<64;o++){
    const float* wr = W2 + (size_t)(h*64+o)*64;
    float a = acc[o];
#pragma unroll
    for (int c=0;c<64;c++) a = fmaf(f[c], wr[c], a);
    acc[o]=a;
  }
  uint4* orow = (uint4*)(x3 + ((r<<7) + (size_t)(h<<6)));
#pragma unroll
  for (int q=0;q<8;q++){
    uint4 v;
    v.x = (uint)f2bf(acc[q*8+0]) | ((uint)f2bf(acc[q*8+1])<<16);
    v.y = (uint)f2bf(acc[q*8+2]) | ((uint)f2bf(acc[q*8+3])<<16);
    v.z = (uint)f2bf(acc[q*8+4]) | ((uint)f2bf(acc[q*8+5])<<16);
    v.w = (uint)f2bf(acc[q*8+6]) | ((uint)f2bf(acc[q*8+7])<<16);
    orow[q]=v;
  }
}

// ---------- BN2+ReLU + maxpool over K ----------
__global__ __launch_bounds__(256) void maxpool_kernel(const ushort* __restrict__ x3,
                                                      const float* __restrict__ S2,
                                                      const float* __restrict__ SS2,
                                                      const float* __restrict__ g2,
                                                      const float* __restrict__ be2,
                                                      float* __restrict__ outp){
  const int lane = threadIdx.x & 63, wv = threadIdx.x >> 6;
  const int bm = blockIdx.x*4 + wv;           // 16384 (b,m) groups
  const int c0 = lane*2, c1 = c0+1;
  float mean0 = S2[c0]*INV_CNT;
  float var0  = fmaf(-mean0, mean0, SS2[c0]*INV_CNT);
  float s0 = g2[c0]*rsqrtf(var0+1e-5f);
  float h0 = fmaf(-mean0, s0, be2[c0]);
  float mean1 = S2[c1]*INV_CNT;
  float var1  = fmaf(-mean1, mean1, SS2[c1]*INV_CNT);
  float s1 = g2[c1]*rsqrtf(var1+1e-5f);
  float h1 = fmaf(-mean1, s1, be2[c1]);
  const uint* rb = (const uint*)(x3 + (size_t)bm*K_SMP*128);
  float mx0 = 0.f, mx1 = 0.f;                 // relu floor
#pragma unroll
  for (int k=0;k<K_SMP;k++){
    uint v = rb[k*64 + lane];
    float a0 = bf2f(v & 0xffffu), a1 = bf2f(v >> 16);
    mx0 = fmaxf(mx0, fmaxf(fmaf(a0, s0, h0), 0.f));
    mx1 = fmaxf(mx1, fmaxf(fmaf(a1, s1, h1), 0.f));
  }
  float2* o2 = (float2*)(outp + (size_t)bm*128);
  o2[lane] = make_float2(mx0, mx1);
}

// ---------- launch ----------
extern "C" void kernel_launch(void* const* d_in, const int* in_sizes, int n_in,
                              void* d_out, int out_size, void* d_ws, size_t ws_size,
                              hipStream_t stream){
  const float* xyz    = (const float*)d_in[0];
  const float* points = (const float*)d_in[1];
  const float* w0  = (const float*)d_in[2];
  const float* b0  = (const float*)d_in[3];
  const float* g0  = (const float*)d_in[4];
  const float* be0 = (const float*)d_in[5];
  const float* w1  = (const float*)d_in[6];
  const float* b1  = (const float*)d_in[7];
  const float* g1  = (const float*)d_in[8];
  const float* be1 = (const float*)d_in[9];
  const float* w2  = (const float*)d_in[10];
  const float* b2  = (const float*)d_in[11];
  const float* g2  = (const float*)d_in[12];
  const float* be2 = (const float*)d_in[13];

  float* out      = (float*)d_out;
  float* newxyz   = out;                        // [16,1024,3]
  float* outp     = out + (size_t)B_SZ*M_PTS*3; // [16,1024,128]

  char* ws = (char*)d_ws;
  int*   gidx  = (int*)ws;
  float* stats = (float*)(ws + (2u<<20));
  float* S0 = stats,      *SS0 = stats+64;
  float* S1 = stats+128,  *SS1 = stats+192;
  float* S2 = stats+256,  *SS2 = stats+384;
  ushort* x1 = (ushort*)(ws + (4u<<20));
  ushort* x3 = (ushort*)(ws + (4u<<20));
  ushort* x2 = (ushort*)(ws + (4u<<20) + 134217728u);

  hipMemsetAsync(stats, 0, 512*sizeof(float), stream);
  fps_kernel  <<<B_SZ, 256, 0, stream>>>(xyz, newxyz);
  ballq_kernel<<<1024, 256, 0, stream>>>(xyz, newxyz, gidx);
  conv0_kernel<<<NROWS/256, 256, 0, stream>>>(xyz, points, newxyz, gidx, w0, b0, x1);
  stats_kernel<64><<<1024, 256, 0, stream>>>(x1, S0, SS0);
  conv1_kernel<<<NROWS/256, 256, 0, stream>>>(x1, S0, SS0, g0, be0, w1, b1, x2);
  stats_kernel<64><<<1024, 256, 0, stream>>>(x2, S1, SS1);
  conv2_kernel<<<NROWS/128, 256, 0, stream>>>(x2, S1, SS1, g1, be1, w2, b2, x3);
  stats_kernel<128><<<1024, 256, 0, stream>>>(x3, S2, SS2);
  maxpool_kernel<<<NROWS/128, 256, 0, stream>>>(x3, S2, SS2, g2, be2, outp);
}